// Round 4
// baseline (208.546 us; speedup 1.0000x reference)
//
#include <hip/hip_runtime.h>

#define UNITS 20

typedef __attribute__((ext_vector_type(8))) short short8;
typedef __attribute__((ext_vector_type(4))) float floatx4;
typedef __attribute__((ext_vector_type(4))) unsigned int u32x4;
typedef unsigned int u32;
typedef unsigned short u16;

__device__ __forceinline__ float rcpf_fast(float x) { return __builtin_amdgcn_rcpf(x); }
__device__ __forceinline__ float sigmoidf_fast(float x) { return rcpf_fast(1.0f + __expf(-x)); }
__device__ __forceinline__ float tanhf_fast(float x) { return 1.0f - 2.0f * rcpf_fast(1.0f + __expf(2.0f * x)); }

__device__ __forceinline__ u32 f2bf(float f) {
  u32 u = __builtin_bit_cast(u32, f);
  u += 0x7fffu + ((u >> 16) & 1u);   // RNE
  return u >> 16;
}
__device__ __forceinline__ u32 pack2(float a, float b) { return f2bf(a) | (f2bf(b) << 16); }
__device__ __forceinline__ short8 pack8(float4 a, float4 b) {
  u32x4 w;
  w[0] = pack2(a.x, a.y); w[1] = pack2(a.z, a.w);
  w[2] = pack2(b.x, b.y); w[3] = pack2(b.z, b.w);
  return __builtin_bit_cast(short8, w);
}

// ---------------------------------------------------------------------------
// Prep (unchanged from R3): A-operand fragments for the transposed GEMMs.
//  gates^T = Wcat . Z^T, tile t row r = permuted gate row (r&3)*20+(r>>2)*5+t
//    so acc[t][reg] (lane q,m) = gate[reg*20 + q*5 + t] of batch row m.
//  lateral^T = W_lat . Hl^T, identity rows. bias4[u] = (bi,bf,bg,bo).
// ---------------------------------------------------------------------------
__global__ void prep_kernel(const float* __restrict__ W_ih, const float* __restrict__ W_hh,
                            const float* __restrict__ b_ih, const float* __restrict__ b_hh,
                            const float* __restrict__ W_lat,
                            u16* __restrict__ fragsG, u16* __restrict__ fragsL,
                            float4* __restrict__ bias4) {
  int tid = threadIdx.x;
  for (int e = tid; e < 768; e += 256) {
    int fi = e >> 6, lane = e & 63;
    int r = lane & 15, q = lane >> 4;
    short8 v8;
    if (fi < 10) {
      int t = fi >> 1, cc = fi & 1;
      int gr = (r & 3) * 20 + (r >> 2) * 5 + t;
#pragma unroll
      for (int j = 0; j < 8; ++j) {
        int k = cc * 32 + q * 8 + j;
        float v = 0.0f;
        if (k < 20) v = W_ih[gr * UNITS + k];
        else if (k < 40) v = W_hh[gr * UNITS + (k - 20)];
        v8[j] = (short)f2bf(v);
      }
      *(short8*)(fragsG + (size_t)e * 8) = v8;
    } else {
      int t = fi - 10;
      int vr = t * 16 + r;
#pragma unroll
      for (int j = 0; j < 8; ++j) {
        int k = q * 8 + j;
        float v = (vr < 20 && k < 20) ? W_lat[vr * UNITS + k] : 0.0f;
        v8[j] = (short)f2bf(v);
      }
      *(short8*)(fragsL + (size_t)(t * 64 + lane) * 8) = v8;
    }
  }
  if (tid < 20)
    bias4[tid] = make_float4(b_ih[tid] + b_hh[tid],
                             b_ih[20 + tid] + b_hh[20 + tid],
                             b_ih[40 + tid] + b_hh[40 + tid],
                             b_ih[60 + tid] + b_hh[60 + tid]);
}

// ---------------------------------------------------------------------------
// Main: 256 threads = 4 INDEPENDENT waves; each wave owns 16 batch rows.
// No __syncthreads. Only LDS use: per-wave 16x40 bf16 h_lstm transpose,
// fenced by in-wave s_waitcnt lgkmcnt(0).
// ---------------------------------------------------------------------------
__global__ __launch_bounds__(256) void stn_main(
    const float* __restrict__ x, const float* __restrict__ h, const float* __restrict__ c,
    const u16* __restrict__ fragsG, const u16* __restrict__ fragsL,
    const float4* __restrict__ bias4, float* __restrict__ out, int B) {
  __shared__ u16 HlAll[4][16 * 40];   // per-wave region; row stride 40 u16 = 80 B (16B-aligned)

  const int tid = threadIdx.x;
  const int lane = tid & 63;
  const int wv = tid >> 6;
  const int m = lane & 15, q = lane >> 4;
  u16* Hl = HlAll[wv];

  const long row = (long)blockIdx.x * 64 + wv * 16 + m;
  const bool live = row < B;
  const long rowc = live ? row : (long)(B - 1);

  // ---- gate B-frag (Z^T) straight from global: z = [x(20) | h(20) | 0(24)] ----
  const float4* x4 = (const float4*)x + rowc * 5;
  const float4* h4 = (const float4*)h + rowc * 5;
  int j0 = q * 2;
  float4 f0 = (j0 < 5) ? x4[j0] : h4[j0 - 5];
  float4 f1 = (j0 + 1 < 5) ? x4[j0 + 1] : h4[j0 - 4];
  short8 bfr0 = pack8(f0, f1);
  short8 bfr1 = (short8){0, 0, 0, 0, 0, 0, 0, 0};
  if (q == 0) bfr1 = pack8(h4[3], h4[4]);   // k = 32..39 = h[12..19]

  // ---- c direct loads: units q*5..q*5+4 of row m ----
  const float* cp = c + rowc * 20 + q * 5;
  float cvv[5];
#pragma unroll
  for (int t = 0; t < 5; ++t) cvv[t] = cp[t];

  // ---- gate GEMM ----
  floatx4 acc[5];
#pragma unroll
  for (int t = 0; t < 5; ++t) {
    float4 b4 = bias4[q * 5 + t];
    acc[t] = (floatx4){b4.x, b4.y, b4.z, b4.w};
    short8 af0 = *(const short8*)(fragsG + (size_t)((t * 2 + 0) * 64 + lane) * 8);
    acc[t] = __builtin_amdgcn_mfma_f32_16x16x32_bf16(af0, bfr0, acc[t], 0, 0, 0);
    short8 af1 = *(const short8*)(fragsG + (size_t)((t * 2 + 1) * 64 + lane) * 8);
    acc[t] = __builtin_amdgcn_mfma_f32_16x16x32_bf16(af1, bfr1, acc[t], 0, 0, 0);
  }

  // ---- zero Hl pad (k = 20..31 of my row) ----
  {
    u16* zp = Hl + m * 40 + 20 + q * 3;
    zp[0] = 0; zp[1] = 0; zp[2] = 0;
  }

  // ---- LSTM pointwise, all in-lane: acc[t] = {i,f,g,o} of unit u = q*5+t ----
  float cnv[5];
#pragma unroll
  for (int t = 0; t < 5; ++t) {
    float ig = sigmoidf_fast(acc[t][0]);
    float fg = sigmoidf_fast(acc[t][1]);
    float gg = tanhf_fast(acc[t][2]);
    float og = sigmoidf_fast(acc[t][3]);
    float cn = fg * cvv[t] + ig * gg;
    cnv[t] = cn;
    Hl[m * 40 + q * 5 + t] = (u16)f2bf(og * tanhf_fast(cn));
  }

  // in-wave LDS fence: all 64 lanes' writes retire before any lane reads
  asm volatile("s_waitcnt lgkmcnt(0)" ::: "memory");

  // ---- lateral GEMM: out^T = W_lat . Hl^T (K=32) ----
  short8 bl = *(const short8*)(Hl + m * 40 + q * 8);
  short8 al0 = *(const short8*)(fragsL + (size_t)(0 * 64 + lane) * 8);
  short8 al1 = *(const short8*)(fragsL + (size_t)(1 * 64 + lane) * 8);
  floatx4 z4 = (floatx4){0.f, 0.f, 0.f, 0.f};
  floatx4 accL0 = __builtin_amdgcn_mfma_f32_16x16x32_bf16(al0, bl, z4, 0, 0, 0);
  floatx4 accL1 = __builtin_amdgcn_mfma_f32_16x16x32_bf16(al1, bl, z4, 0, 0, 0);

  // ---- direct global stores ----
  if (live) {
    float* oh = out + row * 20;
    float* oc = out + (size_t)B * 20 + row * 20;
    // h_next: accL0[reg] = unit q*4+reg -> 16B-aligned float4
    *(float4*)(oh + q * 4) = make_float4(tanhf_fast(accL0[0]), tanhf_fast(accL0[1]),
                                         tanhf_fast(accL0[2]), tanhf_fast(accL0[3]));
    if (q == 0)  // accL1[reg] = unit 16+reg
      *(float4*)(oh + 16) = make_float4(tanhf_fast(accL1[0]), tanhf_fast(accL1[1]),
                                        tanhf_fast(accL1[2]), tanhf_fast(accL1[3]));
#pragma unroll
    for (int t = 0; t < 5; ++t) oc[q * 5 + t] = cnv[t];
  }
}

extern "C" void kernel_launch(void* const* d_in, const int* in_sizes, int n_in,
                              void* d_out, int out_size, void* d_ws, size_t ws_size,
                              hipStream_t stream) {
  const float* x     = (const float*)d_in[0];
  const float* h     = (const float*)d_in[1];
  const float* c     = (const float*)d_in[2];
  const float* W_ih  = (const float*)d_in[3];
  const float* W_hh  = (const float*)d_in[4];
  const float* b_ih  = (const float*)d_in[5];
  const float* b_hh  = (const float*)d_in[6];
  const float* W_lat = (const float*)d_in[7];
  float* out = (float*)d_out;

  u16*    fragsG = (u16*)d_ws;                      // 10*64*8*2 = 10240 B
  u16*    fragsL = (u16*)((char*)d_ws + 10240);     //  2*64*8*2 =  2048 B
  float4* bias4  = (float4*)((char*)d_ws + 12288);  //  20*16    =   320 B

  int B = in_sizes[0] / UNITS;
  prep_kernel<<<1, 256, 0, stream>>>(W_ih, W_hh, b_ih, b_hh, W_lat, fragsG, fragsL, bias4);
  int grid = (B + 63) / 64;
  stn_main<<<grid, 256, 0, stream>>>(x, h, c, fragsG, fragsL, bias4, out, B);
}